// Round 1
// baseline (62.415 us; speedup 1.0000x reference)
//
#include <hip/hip_runtime.h>
#include <stdint.h>

// Problem geometry (fixed by reference):
//   preds      [8, 21, 512, 512] f32
//   embeddings [8, 128, 128, 128] f32
//   gts        [8, 512, 512] i32  (unused)
//   fsss_gts   [8, 512, 512] i32
//   pos_memory [1000, 128] f32
//   neg_memory [1000, 128] f32
//   out: scalar f32
// Downsample 512->128 nearest picks rows/cols 4i, 4j exactly.

#define N_POS 131072   // 8*128*128
#define NBLK  512      // N_POS / 256
#define MEMSZ 1000
#define KANC  100      // MEM/10
#define KPN   333      // MEM/3
#define SLOT_POS 100   // Esel slot base for positives
#define SLOT_NEG 433   // Esel slot base for negatives
#define NSLOTS 766

// ---------------- K1: argmax + masks + per-block counts ----------------
__global__ void mask_kernel(const float* __restrict__ preds,
                            const int* __restrict__ fsss,
                            uint8_t* __restrict__ flags,
                            int* __restrict__ blockCounts) {
    int n = blockIdx.x * 256 + threadIdx.x;
    int b = n >> 14;
    int i = (n >> 7) & 127;
    int j = n & 127;
    int row = i << 2, col = j << 2;

    const float* p = preds + (((size_t)b * 21) * 512 + row) * 512 + col;
    float best = p[0];
    int bc = 0;
#pragma unroll
    for (int c = 1; c < 21; ++c) {
        float v = p[(size_t)c * 262144];
        if (v > best) { best = v; bc = c; }   // strict > = first-max (jnp.argmax)
    }
    int fv = fsss[((size_t)b * 512 + row) * 512 + col];

    bool pm = (bc != 0);
    bool fm = (fv != 0) && (fv != 255);
    bool anchor   = pm && fm;           // pred & fsss
    bool positive = (!pm) && fm;        // fsss & ~pred
    bool negative = pm && (fv == 0);    // pred & (fsss==0)
    flags[n] = (uint8_t)((int)anchor | ((int)positive << 1) | ((int)negative << 2));

    __shared__ int cnt[3];
    if (threadIdx.x < 3) cnt[threadIdx.x] = 0;
    __syncthreads();
    if (anchor)   atomicAdd(&cnt[0], 1);
    if (positive) atomicAdd(&cnt[1], 1);
    if (negative) atomicAdd(&cnt[2], 1);
    __syncthreads();
    if (threadIdx.x < 3) blockCounts[threadIdx.x * NBLK + blockIdx.x] = cnt[threadIdx.x];
}

// ---------------- K2: exclusive scan of block counts (1 block, 512 thr) ----------------
__global__ void scan_kernel(const int* __restrict__ blockCounts,
                            int* __restrict__ blockOffsets,
                            int* __restrict__ totals) {
    __shared__ int s[NBLK];
    int t = threadIdx.x;
    for (int cat = 0; cat < 3; ++cat) {
        int x = blockCounts[cat * NBLK + t];
        s[t] = x;
        __syncthreads();
        for (int off = 1; off < NBLK; off <<= 1) {
            int v = (t >= off) ? s[t - off] : 0;
            __syncthreads();
            s[t] += v;
            __syncthreads();
        }
        blockOffsets[cat * NBLK + t] = s[t] - x;   // exclusive
        if (t == NBLK - 1) totals[cat] = s[t];
        __syncthreads();
    }
}

// ---------------- K3: global rank + first-k index selection ----------------
__global__ void select_kernel(const uint8_t* __restrict__ flags,
                              const int* __restrict__ blockOffsets,
                              int* __restrict__ idx) {
    int n = blockIdx.x * 256 + threadIdx.x;
    uint8_t f = flags[n];
    int lane = threadIdx.x & 63;
    int wave = threadIdx.x >> 6;
    __shared__ int wtot[3][4];
    unsigned long long masks[3];
#pragma unroll
    for (int cat = 0; cat < 3; ++cat) {
        int bit = (f >> cat) & 1;
        unsigned long long m = __ballot(bit);
        masks[cat] = m;
        if (lane == 0) wtot[cat][wave] = (int)__popcll(m);
    }
    __syncthreads();
    const int kcap[3] = {KANC, KPN, KPN};
    const int base[3] = {0, SLOT_POS, SLOT_NEG};
#pragma unroll
    for (int cat = 0; cat < 3; ++cat) {
        if (!((f >> cat) & 1)) continue;
        int woff = 0;
#pragma unroll
        for (int w = 0; w < 4; ++w) if (w < wave) woff += wtot[cat][w];
        int intra = woff + (int)__popcll(masks[cat] & ((1ull << lane) - 1ull));
        int rank = blockOffsets[cat * NBLK + blockIdx.x] + intra;
        if (rank < kcap[cat]) idx[base[cat] + rank] = n;
    }
}

// ---------------- K4: normalize selected embedding rows ----------------
__global__ void normalize_kernel(const float* __restrict__ emb,
                                 const int* __restrict__ idx,
                                 const int* __restrict__ totals,
                                 float* __restrict__ Esel) {
    int slot = blockIdx.x;
    int A = min(KANC, totals[0]);
    int P = min(KPN, totals[1]);
    int Q = min(KPN, totals[2]);
    bool valid;
    if (slot < SLOT_POS)      valid = slot < A;
    else if (slot < SLOT_NEG) valid = (slot - SLOT_POS) < P;
    else                      valid = (slot - SLOT_NEG) < Q;
    if (!valid) return;   // block-uniform

    int n = idx[slot];
    int b = n >> 14;
    int ij = n & 16383;
    int d = threadIdx.x;
    float v = emb[((size_t)b * 128 + d) * 16384 + ij];

    __shared__ float red[128];
    red[d] = v * v;
    __syncthreads();
    for (int off = 64; off > 0; off >>= 1) {
        if (d < off) red[d] += red[d + off];
        __syncthreads();
    }
    float norm = sqrtf(red[0]);
    float scale = 1.0f / fmaxf(norm, 1e-12f);
    Esel[(size_t)slot * 128 + d] = v * scale;
}

// ---------------- K5: anchor sum (1 block, 128 thr) ----------------
__global__ void ancsum_kernel(const float* __restrict__ Esel,
                              const int* __restrict__ totals,
                              float* __restrict__ ancSum) {
    int A = min(KANC, totals[0]);
    int d = threadIdx.x;
    float acc = 0.f;
    for (int r = 0; r < A; ++r) acc += Esel[(size_t)r * 128 + d];
    ancSum[d] = acc;
}

// ---------------- K6: memory sums (pos/neg, 8 partials each) ----------------
__global__ void memsum_kernel(const float* __restrict__ posMem,
                              const float* __restrict__ negMem,
                              const float* __restrict__ Esel,
                              const int* __restrict__ totals,
                              float* __restrict__ partials) {
    int memSel = blockIdx.x >> 3;      // 0 = pos, 1 = neg
    int part = blockIdx.x & 7;
    int d = threadIdx.x;
    const float* mem = memSel ? negMem : posMem;
    int cnt = min(KPN, totals[memSel ? 2 : 1]);
    int baseSlot = memSel ? SLOT_NEG : SLOT_POS;
    float acc = 0.f;
    int m0 = part * 125, m1 = m0 + 125;
    for (int m = m0; m < m1; ++m) {
        float v = (m < cnt) ? Esel[(size_t)(baseSlot + m) * 128 + d]
                            : mem[(size_t)m * 128 + d];
        acc += v;
    }
    partials[(size_t)blockIdx.x * 128 + d] = acc;
}

// ---------------- K7: final dot + relu ----------------
__global__ void final_kernel(const float* __restrict__ ancSum,
                             const float* __restrict__ partials,
                             const int* __restrict__ totals,
                             float* __restrict__ out) {
    int d = threadIdx.x;
    float pos = 0.f, neg = 0.f;
#pragma unroll
    for (int p = 0; p < 8; ++p)  pos += partials[p * 128 + d];
#pragma unroll
    for (int p = 8; p < 16; ++p) neg += partials[p * 128 + d];
    double prod = (double)ancSum[d] * ((double)pos - (double)neg);
    __shared__ double red[128];
    red[d] = prod;
    __syncthreads();
    for (int off = 64; off > 0; off >>= 1) {
        if (d < off) red[d] += red[d + off];
        __syncthreads();
    }
    if (d == 0) {
        int A = min(KANC, totals[0]);
        double nAnc = (A > 0) ? (double)A : 1.0;
        double v = red[0] / (nAnc * (double)MEMSZ) + 0.2;
        out[0] = (float)(v > 0.0 ? v : 0.0);
    }
}

extern "C" void kernel_launch(void* const* d_in, const int* in_sizes, int n_in,
                              void* d_out, int out_size, void* d_ws, size_t ws_size,
                              hipStream_t stream) {
    const float* preds  = (const float*)d_in[0];
    const float* emb    = (const float*)d_in[1];
    // d_in[2] = gts, unused by the loss
    const int* fsss     = (const int*)d_in[3];
    const float* posMem = (const float*)d_in[4];
    const float* negMem = (const float*)d_in[5];
    float* out = (float*)d_out;

    char* ws = (char*)d_ws;
    uint8_t* flags    = (uint8_t*)ws;                      // 131072 B
    int* blockCounts  = (int*)(ws + 131072);               // 3*512
    int* blockOffsets = blockCounts + 3 * NBLK;            // 3*512
    int* totals       = blockOffsets + 3 * NBLK;           // 3 (+1 pad)
    int* idx          = totals + 4;                        // 766 (+pad to 768)
    float* Esel       = (float*)(idx + 768);               // 766*128
    float* ancSum     = Esel + NSLOTS * 128;               // 128
    float* partials   = ancSum + 128;                      // 16*128

    mask_kernel<<<NBLK, 256, 0, stream>>>(preds, fsss, flags, blockCounts);
    scan_kernel<<<1, NBLK, 0, stream>>>(blockCounts, blockOffsets, totals);
    select_kernel<<<NBLK, 256, 0, stream>>>(flags, blockOffsets, idx);
    normalize_kernel<<<NSLOTS, 128, 0, stream>>>(emb, idx, totals, Esel);
    ancsum_kernel<<<1, 128, 0, stream>>>(Esel, totals, ancSum);
    memsum_kernel<<<16, 128, 0, stream>>>(posMem, negMem, Esel, totals, partials);
    final_kernel<<<1, 128, 0, stream>>>(ancSum, partials, totals, out);
}